// Round 4
// baseline (315.825 us; speedup 1.0000x reference)
//
#include <hip/hip_runtime.h>
#include <stdint.h>

#define NROW 8192
#define DIM  512
#define NOUT 16
#define GAMMA 0.001f
// exp(2*gamma*c) = exp2(c * 2*gamma*log2(e))
#define EXP2S (2.0f * GAMMA * 1.44269504088896340736f)

typedef __bf16 bf16_t;
typedef bf16_t bf16x4_t __attribute__((ext_vector_type(4)));
typedef bf16_t bf16x8_t __attribute__((ext_vector_type(8)));
typedef float  floatx4_t __attribute__((ext_vector_type(4)));
typedef int    intx4_t  __attribute__((ext_vector_type(4)));

// ---------- prep: fp32 -> bf16 rows, exp(-g*||row||^2), fused alpha' ----------
__global__ __launch_bounds__(256) void prep_convert(
    const float* __restrict__ X, const float* __restrict__ T,
    const float* __restrict__ alpha,
    bf16_t* __restrict__ Xb, bf16_t* __restrict__ Tb,
    float* __restrict__ xfac, bf16_t* __restrict__ alphaTp)
{
    const int w = threadIdx.x >> 6, lane = threadIdx.x & 63;
    const int row = blockIdx.x * 4 + w;              // 0..16383
    const bool is_test = row < NROW;
    const float* src = is_test ? X : T;
    bf16_t* dst = is_test ? Xb : Tb;
    const int r = is_test ? row : row - NROW;
    const float4* s4 = (const float4*)(src + (size_t)r * DIM);
    const float4 v0 = s4[lane];
    const float4 v1 = s4[lane + 64];
    float ss = v0.x*v0.x + v0.y*v0.y + v0.z*v0.z + v0.w*v0.w
             + v1.x*v1.x + v1.y*v1.y + v1.z*v1.z + v1.w*v1.w;
    bf16x4_t o0 = { (bf16_t)v0.x, (bf16_t)v0.y, (bf16_t)v0.z, (bf16_t)v0.w };
    bf16x4_t o1 = { (bf16_t)v1.x, (bf16_t)v1.y, (bf16_t)v1.z, (bf16_t)v1.w };
    bf16x4_t* d4 = (bf16x4_t*)(dst + (size_t)r * DIM);
    d4[lane] = o0;
    d4[lane + 64] = o1;
#pragma unroll
    for (int m = 32; m > 0; m >>= 1) ss += __shfl_xor(ss, m, 64);
    const float f = __expf(-GAMMA * ss);             // all lanes hold the sum
    if (is_test) {
        if (lane == 0) xfac[r] = f;
    } else if (lane < 16) {
        // alphaT'[o][j] = exp(-g*||y_j||^2) * alpha[j][o]
        alphaTp[(size_t)lane * NROW + r] = (bf16_t)(alpha[r * 16 + lane] * f);
    }
}

// ---------- main: 128x128 bf16 MFMA GEMM + fused exp + @alpha' epilogue ----------
// Register-prefetch pipeline: global->VGPR loads for iter k+1 issue during iter
// k's compute; ds_write_b128 stages them next iter. Plain VGPR loads don't force
// the vmcnt(0)-drain-at-barrier that global_load_lds does, so the L2-miss (~600
// cyc) staging latency hides behind MFMA instead of stalling every barrier.
#define BK 64
#define TPT 4        // train tiles per block (16 chunks x 4 tiles = 8192)
#define KLD2 72      // padded row stride (bf16) of per-wave K'' tile [test 64][train 64]

__global__ __launch_bounds__(256, 4) void rbf_main(
    const bf16_t* __restrict__ Xb, const bf16_t* __restrict__ Tb,
    const bf16_t* __restrict__ alphaTp, const float* __restrict__ xfac,
    float* __restrict__ out)
{
    // union: staging Ts[128][64](16KB)+Xs[128][64](16KB)  vs  4 waves x K''[64][72]
    __shared__ __align__(16) unsigned char smem[4 * 64 * KLD2 * 2];   // 36864 B

    const int tid = threadIdx.x;
    const int w = tid >> 6, lane = tid & 63;
    const int wm = w >> 1, wn = w & 1;               // train half / test half
    const int quad = lane >> 4, l15 = lane & 15;

    const int rb = blockIdx.x;                       // 0..63   test block (XCD = rb%8)
    const int chunk = blockIdx.y;                    // 0..15   train chunk
    const int row0 = rb * 128;                       // test base row

    // staging slot s = tid + i*256: row = i*32 + (tid>>3), LDS col16 = tid&7,
    // global col16 = (tid&7) ^ (row&7)   (XOR swizzle)
    const int s_row = tid >> 3;                      // 0..31
    const int g_colb = (((tid & 7) ^ (s_row & 7)) * 16);
    const char* gX  = (const char*)(Xb + (size_t)(row0 + s_row) * DIM) + g_colb;
    const char* gTb = (const char*)(Tb + (size_t)(chunk * (TPT * 128) + s_row) * DIM) + g_colb;

    const floatx4_t vzero = {0.f, 0.f, 0.f, 0.f};
    floatx4_t oacc[4];
#pragma unroll
    for (int i = 0; i < 4; ++i) oacc[i] = vzero;

    bf16_t* kw = (bf16_t*)smem + w * (64 * KLD2);    // this wave's K'' region

    // prime the pipeline: t=0, ki=0
    intx4_t pT[4], pX[4];
#pragma unroll
    for (int i = 0; i < 4; ++i) {
        pT[i] = *(const intx4_t*)(gTb + i * 32768);
        pX[i] = *(const intx4_t*)(gX + i * 32768);
    }

    for (int t = 0; t < TPT; ++t) {
        const int cb = chunk * (TPT * 128) + t * 128;    // train base row
        const char* gT = gTb + (size_t)t * 131072;       // 128 rows * 1024 B

        floatx4_t acc[4][4];
#pragma unroll
        for (int i = 0; i < 4; ++i)
#pragma unroll
            for (int j = 0; j < 4; ++j) acc[i][j] = vzero;

        bf16x8_t bv0, bv1;

#pragma unroll
        for (int ki = 0; ki < 8; ++ki) {
            __syncthreads();                 // all frag reads of prev stage done
            // stage prefetched regs -> LDS (vmcnt wait lands here, after a full
            // compute phase of cover)
#pragma unroll
            for (int i = 0; i < 4; ++i) {
                *(intx4_t*)(smem + i * 4096 + tid * 16)         = pT[i];
                *(intx4_t*)(smem + 16384 + i * 4096 + tid * 16) = pX[i];
            }
            __syncthreads();                 // stage visible to all waves

            // ---- k-half 0 frags ----
            bf16x8_t af[4], bfv[4];
            const int xs0 = ((quad ^ (l15 & 7)) * 16);
#pragma unroll
            for (int i = 0; i < 4; ++i) {
                af[i]  = *(const bf16x8_t*)(smem + (wm * 64 + i * 16 + l15) * 128 + xs0);
                bfv[i] = *(const bf16x8_t*)(smem + 16384 + (wn * 64 + i * 16 + l15) * 128 + xs0);
            }

            // ---- issue next prefetch (covered by the MFMA below) ----
            if (ki < 7) {
#pragma unroll
                for (int i = 0; i < 4; ++i) {
                    pT[i] = *(const intx4_t*)(gT + i * 32768 + (ki + 1) * 128);
                    pX[i] = *(const intx4_t*)(gX + i * 32768 + (ki + 1) * 128);
                }
            } else {
                if (t + 1 < TPT) {
#pragma unroll
                    for (int i = 0; i < 4; ++i) {
                        pT[i] = *(const intx4_t*)(gT + 131072 + i * 32768);
                        pX[i] = *(const intx4_t*)(gX + i * 32768);
                    }
                }
                const bf16_t* ap = alphaTp + (size_t)l15 * NROW + cb + wm * 64 + quad * 8;
                bv0 = *(const bf16x8_t*)(ap);
                bv1 = *(const bf16x8_t*)(ap + 32);
            }

#pragma unroll
            for (int mi = 0; mi < 4; ++mi)
#pragma unroll
                for (int ni = 0; ni < 4; ++ni)
                    acc[mi][ni] = __builtin_amdgcn_mfma_f32_16x16x32_bf16(
                        af[mi], bfv[ni], acc[mi][ni], 0, 0, 0);

            // ---- k-half 1 ----
            const int xs1 = (((4 + quad) ^ (l15 & 7)) * 16);
#pragma unroll
            for (int i = 0; i < 4; ++i) {
                af[i]  = *(const bf16x8_t*)(smem + (wm * 64 + i * 16 + l15) * 128 + xs1);
                bfv[i] = *(const bf16x8_t*)(smem + 16384 + (wn * 64 + i * 16 + l15) * 128 + xs1);
            }
#pragma unroll
            for (int mi = 0; mi < 4; ++mi)
#pragma unroll
                for (int ni = 0; ni < 4; ++ni)
                    acc[mi][ni] = __builtin_amdgcn_mfma_f32_16x16x32_bf16(
                        af[mi], bfv[ni], acc[mi][ni], 0, 0, 0);
        }

        __syncthreads();   // all frag reads of Ts/Xs done before overwrite with K''
        // K'' = exp(2*gamma*cross), bf16, test-major: kw[test][train], 8B packed
        // acc[mi][ni][r] = cross[train = mi*16+quad*4+r][test = ni*16+l15]
#pragma unroll
        for (int ni = 0; ni < 4; ++ni)
#pragma unroll
            for (int mi = 0; mi < 4; ++mi) {
                bf16x4_t pk;
#pragma unroll
                for (int r = 0; r < 4; ++r)
                    pk[r] = (bf16_t)__builtin_amdgcn_exp2f(acc[mi][ni][r] * EXP2S);
                *(bf16x4_t*)(kw + (ni * 16 + l15) * KLD2 + mi * 16 + quad * 4) = pk;
            }
        // no barrier: each wave reads only its own kw region (in-wave lgkmcnt orders)

        // epilogue: oacc[ni] += K''[test 16(ni) x train 64] @ alpha'[train 64 x o 16]
#pragma unroll
        for (int ni = 0; ni < 4; ++ni) {
            const bf16x8_t av0 = *(const bf16x8_t*)(kw + (ni * 16 + l15) * KLD2 + quad * 8);
            oacc[ni] = __builtin_amdgcn_mfma_f32_16x16x32_bf16(av0, bv0, oacc[ni], 0, 0, 0);
        }
#pragma unroll
        for (int ni = 0; ni < 4; ++ni) {
            const bf16x8_t av1 = *(const bf16x8_t*)(kw + (ni * 16 + l15) * KLD2 + 32 + quad * 8);
            oacc[ni] = __builtin_amdgcn_mfma_f32_16x16x32_bf16(av1, bv1, oacc[ni], 0, 0, 0);
        }
        // next t: leading __syncthreads() protects kw reads vs restaging
    }

    // reduce the two train halves (wm=0,1) through LDS, then atomicAdd to out
    __syncthreads();
    float* stash = (float*)smem;
    if (wm == 1) {
#pragma unroll
        for (int ni = 0; ni < 4; ++ni)
            *(floatx4_t*)(stash + wn * 1024 + ni * 256 + lane * 4) = oacc[ni];
    }
    __syncthreads();
    if (wm == 0) {
#pragma unroll
        for (int ni = 0; ni < 4; ++ni) {
            const floatx4_t o2 = *(const floatx4_t*)(stash + wn * 1024 + ni * 256 + lane * 4);
            const int trow = row0 + wn * 64 + ni * 16 + quad * 4;
            const float4 xf = *(const float4*)(xfac + trow);
            atomicAdd(out + (size_t)(trow + 0) * NOUT + l15, (oacc[ni][0] + o2[0]) * xf.x);
            atomicAdd(out + (size_t)(trow + 1) * NOUT + l15, (oacc[ni][1] + o2[1]) * xf.y);
            atomicAdd(out + (size_t)(trow + 2) * NOUT + l15, (oacc[ni][2] + o2[2]) * xf.z);
            atomicAdd(out + (size_t)(trow + 3) * NOUT + l15, (oacc[ni][3] + o2[3]) * xf.w);
        }
    }
}

extern "C" void kernel_launch(void* const* d_in, const int* in_sizes, int n_in,
                              void* d_out, int out_size, void* d_ws, size_t ws_size,
                              hipStream_t stream) {
    (void)in_sizes; (void)n_in; (void)out_size; (void)ws_size;
    const float* X     = (const float*)d_in[0];
    const float* T     = (const float*)d_in[1];
    const float* alpha = (const float*)d_in[2];

    char* ws = (char*)d_ws;
    bf16_t* Xb      = (bf16_t*)ws;                                   // 8 MB
    bf16_t* Tb      = (bf16_t*)(ws + (8u << 20));                    // 8 MB
    float*  xfac    = (float*)(ws + (16u << 20));                    // 32 KB
    bf16_t* alphaTp = (bf16_t*)(ws + (16u << 20) + (64u << 10));     // 256 KB
    float*  out     = (float*)d_out;

    hipMemsetAsync(out, 0, (size_t)NROW * NOUT * sizeof(float), stream);
    prep_convert<<<4096, 256, 0, stream>>>(X, T, alpha, Xb, Tb, xfac, alphaTp);
    dim3 grid(64, 16);   // x = rb (XCD affinity for X), y = chunk
    rbf_main<<<grid, 256, 0, stream>>>(Xb, Tb, alphaTp, xfac, out);
}